// Round 9
// baseline (161.911 us; speedup 1.0000x reference)
//
#include <hip/hip_runtime.h>
#include <hip/hip_fp16.h>
#include <cstdint>
#include <cstddef>
#include <math.h>

// Problem constants (from reference)
#define NNODES 20000
#define NEDGES 320000
#define TDIM   8
#define CDIM   32
#define RROWS  (NNODES * TDIM)           // 160000 rows of 32 floats (= 625*256)
#define NELEM  (RROWS * CDIM)            // 5,120,000 elements per [N,T,C] tensor
#define ROWBLK (TDIM * CDIM)             // 256 floats per node

static __device__ __forceinline__ float4 fmax4(float4 a, float4 b) {
    return make_float4(fmaxf(a.x, b.x), fmaxf(a.y, b.y),
                       fmaxf(a.z, b.z), fmaxf(a.w, b.w));
}

static __device__ __forceinline__ unsigned pk2(float a, float b) {
    __half2 h = __floats2half2_rn(a, b);
    return *reinterpret_cast<unsigned*>(&h);
}

// load 4 halves (8B) and convert to float4
static __device__ __forceinline__ float4 ld4h(const char* p) {
    uint2 v = *(const uint2*)p;
    __half2 h0 = *reinterpret_cast<__half2*>(&v.x);
    __half2 h1 = *reinterpret_cast<__half2*>(&v.y);
    float2 f0 = __half22float2(h0);
    float2 f1 = __half22float2(h1);
    return make_float4(f0.x, f0.y, f1.x, f1.y);
}

// ---------------------------------------------------------------------------
// WU = W @ U (32x32 @ 32x32), one block of 1024 threads, thread = (k,c).
// Lets linear2 compute h = x@W and hu = x@WU as two INDEPENDENT accumulations
// in a single pass over x (reference computes (x@W)@U; f32-rounding-equivalent).
// ---------------------------------------------------------------------------
__global__ __launch_bounds__(1024) void wu_kernel(
    const float* __restrict__ W, const float* __restrict__ U,
    float* __restrict__ WU)
{
    int t = threadIdx.x;
    int k = t >> 5, c = t & 31;
    float acc = 0.f;
#pragma unroll
    for (int j = 0; j < CDIM; ++j) acc = fmaf(W[k * CDIM + j], U[j * CDIM + c], acc);
    WU[k * CDIM + c] = acc;
}

// ---------------------------------------------------------------------------
// Fused linear kernel: h = x @ W ; hu16 = half(x @ WU).  One row per thread.
// Design notes (R6/R7 post-mortem: fully-unrolled 2048-FMA bodies ran at
// 45us with 8% VALUBusy regardless of LDS vs s_load weight path -> I$ bloat
// + exposed per-k latency):
//  - k-loop is ROLLED (#pragma unroll 2): body ~1KB, I$-resident.
//  - x row staged in LDS (stride 33, conflict-free) so runtime-k indexing
//    doesn't force a register array to scratch (rule: runtime-indexed
//    arrays spill).
//  - weight rows read via wave-uniform s_load (SGPR operand of v_fmac).
//  - hr[32]/acc[32] only ever indexed by compile-time c -> stay in VGPRs.
//  - h and hu accumulations are independent -> 2x ILP per xk.
// ---------------------------------------------------------------------------
__global__ __launch_bounds__(256, 2) void linear2_kernel(
    const float* __restrict__ in,   // [RROWS, 32]
    const float* __restrict__ W,    // [32, 32]
    const float* __restrict__ WU,   // [32, 32] = W@U precomputed
    float* __restrict__ h,          // [RROWS, 32] f32
    __half* __restrict__ hu16)      // [RROWS, 32] fp16
{
    __shared__ float sx[256][33];   // 33KB, stride-33 -> conflict-free
    int tid = threadIdx.x;
    int row = blockIdx.x * 256 + tid;        // RROWS == 625*256 exactly

    const float4* in4 = (const float4*)(in + (size_t)row * CDIM);
#pragma unroll
    for (int q = 0; q < 8; ++q) {
        float4 v = in4[q];
        sx[tid][4 * q + 0] = v.x; sx[tid][4 * q + 1] = v.y;
        sx[tid][4 * q + 2] = v.z; sx[tid][4 * q + 3] = v.w;
    }
    // each thread reads only its own LDS row -> no barrier needed

    float hr[CDIM], acc[CDIM];
#pragma unroll
    for (int c = 0; c < CDIM; ++c) { hr[c] = 0.f; acc[c] = 0.f; }

#pragma unroll 2
    for (int k = 0; k < CDIM; ++k) {
        float xk = sx[tid][k];               // ds_read_b32, runtime k OK
        const float* wr  = W  + k * CDIM;    // uniform -> s_load row (128B)
        const float* wur = WU + k * CDIM;    // uniform -> s_load row (128B)
#pragma unroll
        for (int c = 0; c < CDIM; ++c) {
            hr[c]  = fmaf(xk, wr[c],  hr[c]);
            acc[c] = fmaf(xk, wur[c], acc[c]);
        }
    }

    float* hrow = h + (size_t)row * CDIM;
#pragma unroll
    for (int q = 0; q < 8; ++q) {
        ((float4*)hrow)[q] = make_float4(hr[4 * q], hr[4 * q + 1],
                                         hr[4 * q + 2], hr[4 * q + 3]);
    }

    uint4* dst = (uint4*)((char*)hu16 + (size_t)row * 64);
#pragma unroll
    for (int q = 0; q < 4; ++q) {
        dst[q] = make_uint4(pk2(acc[8 * q + 0], acc[8 * q + 1]),
                            pk2(acc[8 * q + 2], acc[8 * q + 3]),
                            pk2(acc[8 * q + 4], acc[8 * q + 5]),
                            pk2(acc[8 * q + 6], acc[8 * q + 7]));
    }
}

// ---------------------------------------------------------------------------
// CSR build: hist -> 3-stage parallel scan -> scatter.  Once per launch.
// ---------------------------------------------------------------------------
__global__ __launch_bounds__(256) void zero_counts_kernel(int* __restrict__ counts)
{
    int i = blockIdx.x * 256 + threadIdx.x;
    if (i < NNODES) counts[i] = 0;
}

__global__ __launch_bounds__(256) void hist_kernel(
    const int* __restrict__ ei, int* __restrict__ counts)
{
    int e = blockIdx.x * 256 + threadIdx.x;
    if (e < NEDGES) atomicAdd(&counts[ei[NEDGES + e]], 1);
}

__global__ __launch_bounds__(256) void blocksum_kernel(
    const int* __restrict__ counts, int* __restrict__ bsum)
{
    __shared__ int sd[256];
    int tid = threadIdx.x;
    int i = blockIdx.x * 256 + tid;
    sd[tid] = (i < NNODES) ? counts[i] : 0;
    __syncthreads();
#pragma unroll
    for (int off = 128; off > 0; off >>= 1) {
        if (tid < off) sd[tid] += sd[tid + off];
        __syncthreads();
    }
    if (tid == 0) bsum[blockIdx.x] = sd[0];
}

__global__ __launch_bounds__(128) void bscan_kernel(
    const int* __restrict__ bsum, int* __restrict__ bbase, int nblocks)
{
    __shared__ int sd[128];
    int tid = threadIdx.x;
    int v = (tid < nblocks) ? bsum[tid] : 0;
    sd[tid] = v;
    __syncthreads();
#pragma unroll
    for (int off = 1; off < 128; off <<= 1) {
        int t = (tid >= off) ? sd[tid - off] : 0;
        __syncthreads();
        sd[tid] += t;
        __syncthreads();
    }
    if (tid < nblocks) bbase[tid] = sd[tid] - v;   // exclusive
}

__global__ __launch_bounds__(256) void localscan_kernel(
    const int* __restrict__ counts, const int* __restrict__ bbase,
    int* __restrict__ offsets, int* __restrict__ cursor)
{
    __shared__ int sd[256];
    int tid = threadIdx.x;
    int i = blockIdx.x * 256 + tid;
    int v = (i < NNODES) ? counts[i] : 0;
    sd[tid] = v;
    __syncthreads();
#pragma unroll
    for (int off = 1; off < 256; off <<= 1) {
        int t = (tid >= off) ? sd[tid - off] : 0;
        __syncthreads();
        sd[tid] += t;
        __syncthreads();
    }
    int excl = bbase[blockIdx.x] + sd[tid] - v;
    if (i < NNODES) { offsets[i] = excl; cursor[i] = excl; }
    if (i == NNODES - 1) offsets[NNODES] = NEDGES;
}

__global__ __launch_bounds__(256) void scatter_kernel(
    const int* __restrict__ ei,
    int* __restrict__ cursor,
    int* __restrict__ csr_src)
{
    int e = blockIdx.x * 256 + threadIdx.x;
    if (e < NEDGES) {
        int t = ei[NEDGES + e];
        int pos = atomicAdd(&cursor[t], 1);
        csr_src[pos] = ei[e];
    }
}

// ---------------------------------------------------------------------------
// Aggregation: one wave per node (block = 4 nodes x 1 wave).
// Gather source is fp16 (512B/row, 8B/lane).  Edge loop unrolled by 4 with
// NEXT-iteration csr indices prefetched while current row loads are in
// flight.  Dot = 4 FMA + 3-step shfl in the 8-lane tau group.  32-bit
// addressing.  No LDS/barriers.
// Writes out = leaky_relu(h + agg, 0.01).  `h`/`out` may alias per-thread.
// ---------------------------------------------------------------------------
__global__ __launch_bounds__(256) void agg_kernel(
    const int* __restrict__ offsets,
    const int* __restrict__ csr_src,
    const __half* __restrict__ hu16, // gather source [RROWS,32] fp16
    const float* h,                  // [RROWS,32]
    float* out)                      // [RROWS,32]
{
    int tid = threadIdx.x;
    int n = blockIdx.x * 4 + (tid >> 6);     // node for this wave
    int l64 = tid & 63;                      // tau*8 + li
    uint32_t rowOff = (uint32_t)l64 * 8u;    // byte offset inside 512B row
    const char* hub = (const char*)hu16;

    float4 bv = ld4h(hub + ((uint32_t)n << 9) + rowOff);   // x_i quad

    int k0 = offsets[n];
    int k1 = offsets[n + 1];

    float4 m = make_float4(-INFINITY, -INFINITY, -INFINITY, -INFINITY);

    int k = k0;
    int kend4 = k0 + ((k1 - k0) & ~3);
    int s0, s1, s2, s3;
    if (k < kend4) {
        s0 = csr_src[k + 0]; s1 = csr_src[k + 1];
        s2 = csr_src[k + 2]; s3 = csr_src[k + 3];
    }
    while (k < kend4) {
        const char* p0 = hub + (((uint32_t)s0 << 9) + rowOff);
        const char* p1 = hub + (((uint32_t)s1 << 9) + rowOff);
        const char* p2 = hub + (((uint32_t)s2 << 9) + rowOff);
        const char* p3 = hub + (((uint32_t)s3 << 9) + rowOff);
        uint2 r0 = *(const uint2*)p0;
        uint2 r1 = *(const uint2*)p1;
        uint2 r2 = *(const uint2*)p2;
        uint2 r3 = *(const uint2*)p3;
        k += 4;
        if (k < kend4) {               // prefetch next indices under row latency
            s0 = csr_src[k + 0]; s1 = csr_src[k + 1];
            s2 = csr_src[k + 2]; s3 = csr_src[k + 3];
        }
        float4 a0 = ld4h((const char*)&r0);  // converts in-register
        float4 a1 = ld4h((const char*)&r1);
        float4 a2 = ld4h((const char*)&r2);
        float4 a3 = ld4h((const char*)&r3);
        float q0 = a0.x * bv.x + a0.y * bv.y + a0.z * bv.z + a0.w * bv.w;
        float q1 = a1.x * bv.x + a1.y * bv.y + a1.z * bv.z + a1.w * bv.w;
        float q2 = a2.x * bv.x + a2.y * bv.y + a2.z * bv.z + a2.w * bv.w;
        float q3 = a3.x * bv.x + a3.y * bv.y + a3.z * bv.z + a3.w * bv.w;
        q0 += __shfl_xor(q0, 1); q1 += __shfl_xor(q1, 1);
        q2 += __shfl_xor(q2, 1); q3 += __shfl_xor(q3, 1);
        q0 += __shfl_xor(q0, 2); q1 += __shfl_xor(q1, 2);
        q2 += __shfl_xor(q2, 2); q3 += __shfl_xor(q3, 2);
        q0 += __shfl_xor(q0, 4); q1 += __shfl_xor(q1, 4);
        q2 += __shfl_xor(q2, 4); q3 += __shfl_xor(q3, 4);
        float g0 = 1.f / (1.f + __expf(-q0));
        float g1 = 1.f / (1.f + __expf(-q1));
        float g2 = 1.f / (1.f + __expf(-q2));
        float g3 = 1.f / (1.f + __expf(-q3));
        m = fmax4(m, make_float4(a0.x * g0, a0.y * g0, a0.z * g0, a0.w * g0));
        m = fmax4(m, make_float4(a1.x * g1, a1.y * g1, a1.z * g1, a1.w * g1));
        m = fmax4(m, make_float4(a2.x * g2, a2.y * g2, a2.z * g2, a2.w * g2));
        m = fmax4(m, make_float4(a3.x * g3, a3.y * g3, a3.z * g3, a3.w * g3));
    }
    for (; k < k1; ++k) {
        int s = csr_src[k];
        float4 a0 = ld4h(hub + (((uint32_t)s << 9) + rowOff));
        float q0 = a0.x * bv.x + a0.y * bv.y + a0.z * bv.z + a0.w * bv.w;
        q0 += __shfl_xor(q0, 1);
        q0 += __shfl_xor(q0, 2);
        q0 += __shfl_xor(q0, 4);
        float g0 = 1.f / (1.f + __expf(-q0));
        m = fmax4(m, make_float4(a0.x * g0, a0.y * g0, a0.z * g0, a0.w * g0));
    }

    bool has = (k1 > k0);
    uint32_t nodeOff = (uint32_t)n * 1024u + (uint32_t)l64 * 16u;  // f32 row
    float4 hv = *(const float4*)((const char*)h + nodeOff);
    float ax = has ? m.x : 0.f;
    float ay = has ? m.y : 0.f;
    float az = has ? m.z : 0.f;
    float aw = has ? m.w : 0.f;
    float vx = hv.x + ax, vy = hv.y + ay, vz = hv.z + az, vw = hv.w + aw;
    float4 o;
    o.x = (vx >= 0.f) ? vx : 0.01f * vx;
    o.y = (vy >= 0.f) ? vy : 0.01f * vy;
    o.z = (vz >= 0.f) ? vz : 0.01f * vz;
    o.w = (vw >= 0.f) ? vw : 0.01f * vw;
    *(float4*)((char*)out + nodeOff) = o;
}

// ---------------------------------------------------------------------------
// Orchestration.
// ws: [counts N][offsets N+1][cursor N][bsum 128][bbase 128][WU1 1024]
//     [WU2 1024][csr E][pad][A: NELEM f32][H16: NELEM half]   (~32 MB)
// Layer 1: linear2(X, Wn1, WU1)->h1=A, hu16->H16;  agg(H16, h=A)->c1=A
// Layer 2: linear2(A, Wn2, WU2)->h2=d_out, hu16->H16; agg(H16, h=d_out)->d_out
// ---------------------------------------------------------------------------
extern "C" void kernel_launch(void* const* d_in, const int* in_sizes, int n_in,
                              void* d_out, int out_size, void* d_ws, size_t ws_size,
                              hipStream_t stream)
{
    const float* X   = (const float*)d_in[0];
    const int*   ei  = (const int*)  d_in[1];
    // d_in[2]=edge_attr, d_in[4]=We1, d_in[7]=We2: dead code in reference
    const float* Wn1 = (const float*)d_in[3];
    const float* u1  = (const float*)d_in[5];
    const float* Wn2 = (const float*)d_in[6];
    const float* u2  = (const float*)d_in[8];

    float* out = (float*)d_out;

    int* counts  = (int*)d_ws;
    int* offsets = counts + NNODES;          // NNODES+1
    int* cursor  = offsets + NNODES + 1;
    int* bsum    = cursor + NNODES;          // 128
    int* bbase   = bsum + 128;               // 128
    float* WU1   = (float*)(bbase + 128);    // 1024
    float* WU2   = WU1 + 1024;               // 1024
    int* csr     = (int*)(WU2 + 1024);       // NEDGES
    float*  A   = (float*)(((uintptr_t)(csr + NEDGES) + 255) & ~(uintptr_t)255);
    __half* H16 = (__half*)(A + NELEM);

    const int rowBlocks  = RROWS / 256;            // 625 (exact)
    const int edgeBlocks = (NEDGES + 255) / 256;   // 1250
    const int nodeBlocks = (NNODES + 255) / 256;   // 79
    const int aggBlocks  = NNODES / 4;             // 5000

    // ---- combined weights + CSR build (shared by both layers) ----
    wu_kernel<<<1, 1024, 0, stream>>>(Wn1, u1, WU1);
    wu_kernel<<<1, 1024, 0, stream>>>(Wn2, u2, WU2);
    zero_counts_kernel<<<nodeBlocks, 256, 0, stream>>>(counts);
    hist_kernel<<<edgeBlocks, 256, 0, stream>>>(ei, counts);
    blocksum_kernel<<<nodeBlocks, 256, 0, stream>>>(counts, bsum);
    bscan_kernel<<<1, 128, 0, stream>>>(bsum, bbase, nodeBlocks);
    localscan_kernel<<<nodeBlocks, 256, 0, stream>>>(counts, bbase, offsets, cursor);
    scatter_kernel<<<edgeBlocks, 256, 0, stream>>>(ei, cursor, csr);

    // ---- layer 1 ----
    linear2_kernel<<<rowBlocks, 256, 0, stream>>>(X, Wn1, WU1, A, H16);
    agg_kernel<<<aggBlocks, 256, 0, stream>>>(offsets, csr, H16, A, A);

    // ---- layer 2 ----
    linear2_kernel<<<rowBlocks, 256, 0, stream>>>(A, Wn2, WU2, out, H16);
    agg_kernel<<<aggBlocks, 256, 0, stream>>>(offsets, csr, H16, out, out);
}

// Round 10
// 148.645 us; speedup vs baseline: 1.0893x; 1.0893x over previous
//
#include <hip/hip_runtime.h>
#include <hip/hip_fp16.h>
#include <cstdint>
#include <cstddef>
#include <math.h>

// Problem constants (from reference)
#define NNODES 20000
#define NEDGES 320000
#define TDIM   8
#define CDIM   32
#define RROWS  (NNODES * TDIM)           // 160000 rows of 32 floats (= 2500*64)
#define NELEM  (RROWS * CDIM)            // 5,120,000 elements per [N,T,C] tensor
#define ROWBLK (TDIM * CDIM)             // 256 floats per node

static __device__ __forceinline__ float4 fmax4(float4 a, float4 b) {
    return make_float4(fmaxf(a.x, b.x), fmaxf(a.y, b.y),
                       fmaxf(a.z, b.z), fmaxf(a.w, b.w));
}

static __device__ __forceinline__ unsigned pk2(float a, float b) {
    __half2 h = __floats2half2_rn(a, b);
    return *reinterpret_cast<unsigned*>(&h);
}

// load 4 halves (8B) and convert to float4
static __device__ __forceinline__ float4 ld4h(const char* p) {
    uint2 v = *(const uint2*)p;
    __half2 h0 = *reinterpret_cast<__half2*>(&v.x);
    __half2 h1 = *reinterpret_cast<__half2*>(&v.y);
    float2 f0 = __half22float2(h0);
    float2 f1 = __half22float2(h1);
    return make_float4(f0.x, f0.y, f1.x, f1.y);
}

// ---------------------------------------------------------------------------
// WU = W @ U for both layers in ONE launch (blockIdx selects layer).
// Lets linear2 compute h = x@W and hu = x@WU as two independent accumulations.
// ---------------------------------------------------------------------------
__global__ __launch_bounds__(1024) void wu_kernel(
    const float* __restrict__ W1, const float* __restrict__ U1, float* __restrict__ WU1,
    const float* __restrict__ W2, const float* __restrict__ U2, float* __restrict__ WU2)
{
    const float* W  = blockIdx.x ? W2  : W1;
    const float* U  = blockIdx.x ? U2  : U1;
    float*       WU = blockIdx.x ? WU2 : WU1;
    int t = threadIdx.x;
    int k = t >> 5, c = t & 31;
    float acc = 0.f;
#pragma unroll
    for (int j = 0; j < CDIM; ++j) acc = fmaf(W[k * CDIM + j], U[j * CDIM + c], acc);
    WU[k * CDIM + c] = acc;
}

// ---------------------------------------------------------------------------
// Fused linear kernel: h = x @ W ; hu16 = half(x @ WU).
// R8 post-mortem: 1 thread/row -> 625 blocks -> 2.4 waves/SIMD; all three
// body variants stalled identically (VALUBusy 8%, occupancy 22%).  TLP was
// the bottleneck, not the body.  New geometry:
//   thread = (row, chunk-of-8-outputs): block = 4 waves x 64 rows;
//   chunk = wave id (readfirstlane -> SGPR) so weight rows stay s_load
//   (wave-uniform SGPR operand of v_fmac);
//   x staged once in LDS [64][33] (read sx[lane][k]: 2-way alias, free);
//   grid 2500 blocks = 10000 waves = ~9.8 waves/SIMD -> latency hidden.
// Per-thread work: 512 FMAs (was 2048).
// ---------------------------------------------------------------------------
__global__ __launch_bounds__(256) void linear2_kernel(
    const float* __restrict__ in,   // [RROWS, 32]
    const float* __restrict__ W,    // [32, 32]
    const float* __restrict__ WU,   // [32, 32] = W@U precomputed
    float* __restrict__ h,          // [RROWS, 32] f32
    __half* __restrict__ hu16)      // [RROWS, 32] fp16
{
    __shared__ float sx[64][33];
    int tid = threadIdx.x;
    int rowBase = blockIdx.x * 64;

    // cooperative stage: 64 rows x 8 float4 = 512 float4; 2 per thread,
    // fully coalesced global reads.
    const float4* in4 = (const float4*)(in + (size_t)rowBase * CDIM);
#pragma unroll
    for (int i = 0; i < 2; ++i) {
        int idx = tid + i * 256;            // 0..511
        float4 v = in4[idx];
        int r = idx >> 3, q = idx & 7;
        sx[r][4 * q + 0] = v.x; sx[r][4 * q + 1] = v.y;
        sx[r][4 * q + 2] = v.z; sx[r][4 * q + 3] = v.w;
    }
    __syncthreads();

    int lane  = tid & 63;
    int chunk = __builtin_amdgcn_readfirstlane(tid >> 6);   // 0..3, SGPR
    int row = rowBase + lane;

    float hr[8], acc[8];
#pragma unroll
    for (int j = 0; j < 8; ++j) { hr[j] = 0.f; acc[j] = 0.f; }

    const float* Wc  = W  + chunk * 8;      // uniform -> s_load
    const float* WUc = WU + chunk * 8;      // uniform -> s_load
#pragma unroll 4
    for (int k = 0; k < CDIM; ++k) {
        float xk = sx[lane][k];             // ds_read_b32, const offset
#pragma unroll
        for (int j = 0; j < 8; ++j) {
            hr[j]  = fmaf(xk, Wc[k * CDIM + j],  hr[j]);
            acc[j] = fmaf(xk, WUc[k * CDIM + j], acc[j]);
        }
    }

    float* hp = h + (size_t)row * CDIM + chunk * 8;
    ((float4*)hp)[0] = make_float4(hr[0], hr[1], hr[2], hr[3]);
    ((float4*)hp)[1] = make_float4(hr[4], hr[5], hr[6], hr[7]);

    uint4* up = (uint4*)((char*)hu16 + (size_t)row * 64 + chunk * 16);
    *up = make_uint4(pk2(acc[0], acc[1]), pk2(acc[2], acc[3]),
                     pk2(acc[4], acc[5]), pk2(acc[6], acc[7]));
}

// ---------------------------------------------------------------------------
// CSR build: hist -> 3-stage parallel scan -> scatter.  Once per launch.
// ---------------------------------------------------------------------------
__global__ __launch_bounds__(256) void zero_counts_kernel(int* __restrict__ counts)
{
    int i = blockIdx.x * 256 + threadIdx.x;
    if (i < NNODES) counts[i] = 0;
}

__global__ __launch_bounds__(256) void hist_kernel(
    const int* __restrict__ ei, int* __restrict__ counts)
{
    int e = blockIdx.x * 256 + threadIdx.x;
    if (e < NEDGES) atomicAdd(&counts[ei[NEDGES + e]], 1);
}

__global__ __launch_bounds__(256) void blocksum_kernel(
    const int* __restrict__ counts, int* __restrict__ bsum)
{
    __shared__ int sd[256];
    int tid = threadIdx.x;
    int i = blockIdx.x * 256 + tid;
    sd[tid] = (i < NNODES) ? counts[i] : 0;
    __syncthreads();
#pragma unroll
    for (int off = 128; off > 0; off >>= 1) {
        if (tid < off) sd[tid] += sd[tid + off];
        __syncthreads();
    }
    if (tid == 0) bsum[blockIdx.x] = sd[0];
}

__global__ __launch_bounds__(128) void bscan_kernel(
    const int* __restrict__ bsum, int* __restrict__ bbase, int nblocks)
{
    __shared__ int sd[128];
    int tid = threadIdx.x;
    int v = (tid < nblocks) ? bsum[tid] : 0;
    sd[tid] = v;
    __syncthreads();
#pragma unroll
    for (int off = 1; off < 128; off <<= 1) {
        int t = (tid >= off) ? sd[tid - off] : 0;
        __syncthreads();
        sd[tid] += t;
        __syncthreads();
    }
    if (tid < nblocks) bbase[tid] = sd[tid] - v;   // exclusive
}

__global__ __launch_bounds__(256) void localscan_kernel(
    const int* __restrict__ counts, const int* __restrict__ bbase,
    int* __restrict__ offsets, int* __restrict__ cursor)
{
    __shared__ int sd[256];
    int tid = threadIdx.x;
    int i = blockIdx.x * 256 + tid;
    int v = (i < NNODES) ? counts[i] : 0;
    sd[tid] = v;
    __syncthreads();
#pragma unroll
    for (int off = 1; off < 256; off <<= 1) {
        int t = (tid >= off) ? sd[tid - off] : 0;
        __syncthreads();
        sd[tid] += t;
        __syncthreads();
    }
    int excl = bbase[blockIdx.x] + sd[tid] - v;
    if (i < NNODES) { offsets[i] = excl; cursor[i] = excl; }
    if (i == NNODES - 1) offsets[NNODES] = NEDGES;
}

__global__ __launch_bounds__(256) void scatter_kernel(
    const int* __restrict__ ei,
    int* __restrict__ cursor,
    int* __restrict__ csr_src)
{
    int e = blockIdx.x * 256 + threadIdx.x;
    if (e < NEDGES) {
        int t = ei[NEDGES + e];
        int pos = atomicAdd(&cursor[t], 1);
        csr_src[pos] = ei[e];
    }
}

// ---------------------------------------------------------------------------
// Aggregation: one wave per node (block = 4 nodes x 1 wave).
// Gather source is fp16 (512B/row, 8B/lane).  Edge loop unrolled by 4 with
// NEXT-iteration csr indices prefetched while current row loads are in
// flight.  Dot = 4 FMA + 3-step shfl in the 8-lane tau group.  32-bit
// addressing.  No LDS/barriers.
// Writes out = leaky_relu(h + agg, 0.01).  `h`/`out` may alias per-thread.
// ---------------------------------------------------------------------------
__global__ __launch_bounds__(256) void agg_kernel(
    const int* __restrict__ offsets,
    const int* __restrict__ csr_src,
    const __half* __restrict__ hu16, // gather source [RROWS,32] fp16
    const float* h,                  // [RROWS,32]
    float* out)                      // [RROWS,32]
{
    int tid = threadIdx.x;
    int n = blockIdx.x * 4 + (tid >> 6);     // node for this wave
    int l64 = tid & 63;                      // tau*8 + li
    uint32_t rowOff = (uint32_t)l64 * 8u;    // byte offset inside 512B row
    const char* hub = (const char*)hu16;

    float4 bv = ld4h(hub + ((uint32_t)n << 9) + rowOff);   // x_i quad

    int k0 = offsets[n];
    int k1 = offsets[n + 1];

    float4 m = make_float4(-INFINITY, -INFINITY, -INFINITY, -INFINITY);

    int k = k0;
    int kend4 = k0 + ((k1 - k0) & ~3);
    int s0, s1, s2, s3;
    if (k < kend4) {
        s0 = csr_src[k + 0]; s1 = csr_src[k + 1];
        s2 = csr_src[k + 2]; s3 = csr_src[k + 3];
    }
    while (k < kend4) {
        const char* p0 = hub + (((uint32_t)s0 << 9) + rowOff);
        const char* p1 = hub + (((uint32_t)s1 << 9) + rowOff);
        const char* p2 = hub + (((uint32_t)s2 << 9) + rowOff);
        const char* p3 = hub + (((uint32_t)s3 << 9) + rowOff);
        uint2 r0 = *(const uint2*)p0;
        uint2 r1 = *(const uint2*)p1;
        uint2 r2 = *(const uint2*)p2;
        uint2 r3 = *(const uint2*)p3;
        k += 4;
        if (k < kend4) {               // prefetch next indices under row latency
            s0 = csr_src[k + 0]; s1 = csr_src[k + 1];
            s2 = csr_src[k + 2]; s3 = csr_src[k + 3];
        }
        float4 a0 = ld4h((const char*)&r0);  // converts in-register
        float4 a1 = ld4h((const char*)&r1);
        float4 a2 = ld4h((const char*)&r2);
        float4 a3 = ld4h((const char*)&r3);
        float q0 = a0.x * bv.x + a0.y * bv.y + a0.z * bv.z + a0.w * bv.w;
        float q1 = a1.x * bv.x + a1.y * bv.y + a1.z * bv.z + a1.w * bv.w;
        float q2 = a2.x * bv.x + a2.y * bv.y + a2.z * bv.z + a2.w * bv.w;
        float q3 = a3.x * bv.x + a3.y * bv.y + a3.z * bv.z + a3.w * bv.w;
        q0 += __shfl_xor(q0, 1); q1 += __shfl_xor(q1, 1);
        q2 += __shfl_xor(q2, 1); q3 += __shfl_xor(q3, 1);
        q0 += __shfl_xor(q0, 2); q1 += __shfl_xor(q1, 2);
        q2 += __shfl_xor(q2, 2); q3 += __shfl_xor(q3, 2);
        q0 += __shfl_xor(q0, 4); q1 += __shfl_xor(q1, 4);
        q2 += __shfl_xor(q2, 4); q3 += __shfl_xor(q3, 4);
        float g0 = 1.f / (1.f + __expf(-q0));
        float g1 = 1.f / (1.f + __expf(-q1));
        float g2 = 1.f / (1.f + __expf(-q2));
        float g3 = 1.f / (1.f + __expf(-q3));
        m = fmax4(m, make_float4(a0.x * g0, a0.y * g0, a0.z * g0, a0.w * g0));
        m = fmax4(m, make_float4(a1.x * g1, a1.y * g1, a1.z * g1, a1.w * g1));
        m = fmax4(m, make_float4(a2.x * g2, a2.y * g2, a2.z * g2, a2.w * g2));
        m = fmax4(m, make_float4(a3.x * g3, a3.y * g3, a3.z * g3, a3.w * g3));
    }
    for (; k < k1; ++k) {
        int s = csr_src[k];
        float4 a0 = ld4h(hub + (((uint32_t)s << 9) + rowOff));
        float q0 = a0.x * bv.x + a0.y * bv.y + a0.z * bv.z + a0.w * bv.w;
        q0 += __shfl_xor(q0, 1);
        q0 += __shfl_xor(q0, 2);
        q0 += __shfl_xor(q0, 4);
        float g0 = 1.f / (1.f + __expf(-q0));
        m = fmax4(m, make_float4(a0.x * g0, a0.y * g0, a0.z * g0, a0.w * g0));
    }

    bool has = (k1 > k0);
    uint32_t nodeOff = (uint32_t)n * 1024u + (uint32_t)l64 * 16u;  // f32 row
    float4 hv = *(const float4*)((const char*)h + nodeOff);
    float ax = has ? m.x : 0.f;
    float ay = has ? m.y : 0.f;
    float az = has ? m.z : 0.f;
    float aw = has ? m.w : 0.f;
    float vx = hv.x + ax, vy = hv.y + ay, vz = hv.z + az, vw = hv.w + aw;
    float4 o;
    o.x = (vx >= 0.f) ? vx : 0.01f * vx;
    o.y = (vy >= 0.f) ? vy : 0.01f * vy;
    o.z = (vz >= 0.f) ? vz : 0.01f * vz;
    o.w = (vw >= 0.f) ? vw : 0.01f * vw;
    *(float4*)((char*)out + nodeOff) = o;
}

// ---------------------------------------------------------------------------
// Orchestration.
// ws: [counts N][offsets N+1][cursor N][bsum 128][bbase 128][WU1 1024]
//     [WU2 1024][csr E][pad][A: NELEM f32][H16: NELEM half]   (~32 MB)
// Layer 1: linear2(X, Wn1, WU1)->h1=A, hu16->H16;  agg(H16, h=A)->c1=A
// Layer 2: linear2(A, Wn2, WU2)->h2=d_out, hu16->H16; agg(H16, h=d_out)->d_out
// ---------------------------------------------------------------------------
extern "C" void kernel_launch(void* const* d_in, const int* in_sizes, int n_in,
                              void* d_out, int out_size, void* d_ws, size_t ws_size,
                              hipStream_t stream)
{
    const float* X   = (const float*)d_in[0];
    const int*   ei  = (const int*)  d_in[1];
    // d_in[2]=edge_attr, d_in[4]=We1, d_in[7]=We2: dead code in reference
    const float* Wn1 = (const float*)d_in[3];
    const float* u1  = (const float*)d_in[5];
    const float* Wn2 = (const float*)d_in[6];
    const float* u2  = (const float*)d_in[8];

    float* out = (float*)d_out;

    int* counts  = (int*)d_ws;
    int* offsets = counts + NNODES;          // NNODES+1
    int* cursor  = offsets + NNODES + 1;
    int* bsum    = cursor + NNODES;          // 128
    int* bbase   = bsum + 128;               // 128
    float* WU1   = (float*)(bbase + 128);    // 1024
    float* WU2   = WU1 + 1024;               // 1024
    int* csr     = (int*)(WU2 + 1024);       // NEDGES
    float*  A   = (float*)(((uintptr_t)(csr + NEDGES) + 255) & ~(uintptr_t)255);
    __half* H16 = (__half*)(A + NELEM);

    const int linBlocks  = RROWS / 64;             // 2500 (64 rows/block)
    const int edgeBlocks = (NEDGES + 255) / 256;   // 1250
    const int nodeBlocks = (NNODES + 255) / 256;   // 79
    const int aggBlocks  = NNODES / 4;             // 5000

    // ---- combined weights + CSR build (shared by both layers) ----
    wu_kernel<<<2, 1024, 0, stream>>>(Wn1, u1, WU1, Wn2, u2, WU2);
    zero_counts_kernel<<<nodeBlocks, 256, 0, stream>>>(counts);
    hist_kernel<<<edgeBlocks, 256, 0, stream>>>(ei, counts);
    blocksum_kernel<<<nodeBlocks, 256, 0, stream>>>(counts, bsum);
    bscan_kernel<<<1, 128, 0, stream>>>(bsum, bbase, nodeBlocks);
    localscan_kernel<<<nodeBlocks, 256, 0, stream>>>(counts, bbase, offsets, cursor);
    scatter_kernel<<<edgeBlocks, 256, 0, stream>>>(ei, cursor, csr);

    // ---- layer 1 ----
    linear2_kernel<<<linBlocks, 256, 0, stream>>>(X, Wn1, WU1, A, H16);
    agg_kernel<<<aggBlocks, 256, 0, stream>>>(offsets, csr, H16, A, A);

    // ---- layer 2 ----
    linear2_kernel<<<linBlocks, 256, 0, stream>>>(A, Wn2, WU2, out, H16);
    agg_kernel<<<aggBlocks, 256, 0, stream>>>(offsets, csr, H16, out, out);
}